// Round 1
// baseline (89.140 us; speedup 1.0000x reference)
//
#include <hip/hip_runtime.h>

// Depthwise 3D Gaussian conv (1,3,160,160,160) fp32, K=25, radius=12.
// Kernel is separable (g1 outer product) -> three 1-D passes of 25 taps.

#define NVOX 160
constexpr int KS   = 25;
constexpr int RAD  = 12;
constexpr int PLANE = NVOX * NVOX;        // 25600
constexpr int VOL   = NVOX * NVOX * NVOX; // 4,096,000
constexpr int CHN   = 3;
constexpr int TOT   = CHN * VOL;          // 12,288,000

// Recover the 1-D Gaussian: g1[i] = sum_{j,k} g3[i,j,k]  (since sum(g1)=1).
__global__ void extract_g1(const float* __restrict__ k3, float* __restrict__ g1) {
    int i = blockIdx.x;      // 0..24
    int t = threadIdx.x;     // 0..63
    float s = 0.f;
    for (int e = t; e < KS * KS; e += 64) s += k3[i * KS * KS + e];
#pragma unroll
    for (int off = 32; off > 0; off >>= 1) s += __shfl_down(s, off);
    if (t == 0) g1[i] = s;
}

// Pass along W (contiguous axis). Block = 4 rows x 64 lanes.
__global__ __launch_bounds__(256) void conv_w(const float* __restrict__ in,
                                              float* __restrict__ out,
                                              const float* __restrict__ g1) {
    __shared__ float row[4][NVOX + 2 * RAD];  // 4 x 184
    float g[KS];
#pragma unroll
    for (int t = 0; t < KS; ++t) g[t] = g1[t];

    int tid  = threadIdx.x;
    int r    = tid >> 6;        // wave index = row within block
    int lane = tid & 63;
    int rb   = blockIdx.x;      // 0 .. 3*160*40-1
    int h0   = (rb % 40) * 4;
    int cd   = rb / 40;         // c*160 + d
    int base = cd * PLANE + (h0 + r) * NVOX;

    for (int i = lane; i < NVOX + 2 * RAD; i += 64) {
        int w = i - RAD;
        row[r][i] = (w >= 0 && w < NVOX) ? in[base + w] : 0.f;
    }
    __syncthreads();

    for (int w = lane; w < NVOX; w += 64) {
        float acc = 0.f;
#pragma unroll
        for (int t = 0; t < KS; ++t) acc = fmaf(g[t], row[r][w + t], acc);
        out[base + w] = acc;
    }
}

// Pass along H. Tile 32(h) x 32(w) per (c,d); halo 12 each side.
// Each thread computes 4 consecutive h outputs with a sliding window.
__global__ __launch_bounds__(256) void conv_h(const float* __restrict__ in,
                                              float* __restrict__ out,
                                              const float* __restrict__ g1) {
    __shared__ float tile[56 * 32];
    float g[KS];
#pragma unroll
    for (int t = 0; t < KS; ++t) g[t] = g1[t];

    int tid = threadIdx.x;
    int b   = blockIdx.x;
    int wt  = b % 5;
    int ht  = (b / 5) % 5;
    int cd  = b / 25;           // c*160 + d
    int h0  = ht * 32, w0 = wt * 32;
    int lw  = tid & 31, lh = tid >> 5;   // lw 0..31, lh 0..7

    const float* basep = in + cd * PLANE + w0;
    for (int i = lh; i < 56; i += 8) {
        int h = h0 + i - RAD;
        tile[i * 32 + lw] = (h >= 0 && h < NVOX) ? basep[h * NVOX + lw] : 0.f;
    }
    __syncthreads();

    int hb = lh * 4;
    float a0 = 0.f, a1 = 0.f, a2 = 0.f, a3 = 0.f;
#pragma unroll
    for (int i = 0; i < KS + 3; ++i) {
        float v = tile[(hb + i) * 32 + lw];
        if (i < KS)            a0 = fmaf(g[i],     v, a0);
        if (i >= 1 && i < 26)  a1 = fmaf(g[i - 1], v, a1);
        if (i >= 2 && i < 27)  a2 = fmaf(g[i - 2], v, a2);
        if (i >= 3)            a3 = fmaf(g[i - 3], v, a3);
    }
    float* ob = out + cd * PLANE + (h0 + hb) * NVOX + w0 + lw;
    ob[0 * NVOX] = a0;
    ob[1 * NVOX] = a1;
    ob[2 * NVOX] = a2;
    ob[3 * NVOX] = a3;
}

// Pass along D. Tile 32(d) x 32(w) per (c,h); halo 12 each side.
__global__ __launch_bounds__(256) void conv_d(const float* __restrict__ in,
                                              float* __restrict__ out,
                                              const float* __restrict__ g1) {
    __shared__ float tile[56 * 32];
    float g[KS];
#pragma unroll
    for (int t = 0; t < KS; ++t) g[t] = g1[t];

    int tid = threadIdx.x;
    int b   = blockIdx.x;
    int wt  = b % 5;
    int dt  = (b / 5) % 5;
    int ch  = b / 25;           // c*160 + h
    int c   = ch / NVOX, h = ch % NVOX;
    int d0  = dt * 32, w0 = wt * 32;
    int lw  = tid & 31, lh = tid >> 5;

    const float* basep = in + c * VOL + h * NVOX + w0;
    for (int i = lh; i < 56; i += 8) {
        int d = d0 + i - RAD;
        tile[i * 32 + lw] = (d >= 0 && d < NVOX) ? basep[d * PLANE + lw] : 0.f;
    }
    __syncthreads();

    int db = lh * 4;
    float a0 = 0.f, a1 = 0.f, a2 = 0.f, a3 = 0.f;
#pragma unroll
    for (int i = 0; i < KS + 3; ++i) {
        float v = tile[(db + i) * 32 + lw];
        if (i < KS)            a0 = fmaf(g[i],     v, a0);
        if (i >= 1 && i < 26)  a1 = fmaf(g[i - 1], v, a1);
        if (i >= 2 && i < 27)  a2 = fmaf(g[i - 2], v, a2);
        if (i >= 3)            a3 = fmaf(g[i - 3], v, a3);
    }
    float* ob = out + c * VOL + (d0 + db) * PLANE + h * NVOX + w0 + lw;
    ob[0 * PLANE] = a0;
    ob[1 * PLANE] = a1;
    ob[2 * PLANE] = a2;
    ob[3 * PLANE] = a3;
}

// Fallback (only if ws too small): direct 25^3-tap depthwise conv.
__global__ __launch_bounds__(256) void conv3d_direct(const float* __restrict__ x,
                                                     const float* __restrict__ k3,
                                                     float* __restrict__ out) {
    int idx = blockIdx.x * 256 + threadIdx.x;
    if (idx >= TOT) return;
    int w = idx % NVOX;
    int t = idx / NVOX;
    int h = t % NVOX; t /= NVOX;
    int d = t % NVOX;
    int c = t / NVOX;
    const float* kc = k3 + c * (KS * KS * KS);
    float acc = 0.f;
    for (int i = 0; i < KS; ++i) {
        int dd = d + i - RAD;
        if (dd < 0 || dd >= NVOX) continue;
        for (int j = 0; j < KS; ++j) {
            int hh = h + j - RAD;
            if (hh < 0 || hh >= NVOX) continue;
            const float* xr = x + (c * NVOX + dd) * NVOX * NVOX + hh * NVOX + (w - RAD);
            const float* kr = kc + (i * KS + j) * KS;
            int k0 = (RAD - w) > 0 ? (RAD - w) : 0;
            int k1 = (NVOX + RAD - w) < KS ? (NVOX + RAD - w) : KS;
            for (int k = k0; k < k1; ++k) acc += kr[k] * xr[k];
        }
    }
    out[idx] = acc;
}

extern "C" void kernel_launch(void* const* d_in, const int* in_sizes, int n_in,
                              void* d_out, int out_size, void* d_ws, size_t ws_size,
                              hipStream_t stream) {
    const float* x  = (const float*)d_in[0];
    const float* k3 = (const float*)d_in[1];
    float* out = (float*)d_out;

    size_t need = 4096 + (size_t)TOT * sizeof(float);
    if (ws_size >= need) {
        float* g1  = (float*)d_ws;
        float* tmp = (float*)((char*)d_ws + 4096);
        extract_g1<<<KS, 64, 0, stream>>>(k3, g1);
        // W pass: x -> out
        conv_w<<<CHN * NVOX * (NVOX / 4), 256, 0, stream>>>(x, out, g1);
        // H pass: out -> tmp
        conv_h<<<CHN * NVOX * 25, 256, 0, stream>>>(out, tmp, g1);
        // D pass: tmp -> out
        conv_d<<<CHN * NVOX * 25, 256, 0, stream>>>(tmp, out, g1);
    } else {
        conv3d_direct<<<(TOT + 255) / 256, 256, 0, stream>>>(x, k3, out);
    }
}

// Round 2
// 74.728 us; speedup vs baseline: 1.1929x; 1.1929x over previous
//
#include <hip/hip_runtime.h>

// Depthwise 3D Gaussian conv (1,3,160,160,160) fp32, K=25, radius=12.
// Separable: three 1-D passes. Each pass: full-axis LDS tile (184 rows of
// 16 float2), 20 outputs/thread (10 conv-axis x 2 packed), v_pk_fma_f32.

#define NV 160
constexpr int KS    = 25;
constexpr int RAD   = 12;
constexpr int PLANE = NV * NV;        // 25600
constexpr int VOL   = NV * NV * NV;   // 4,096,000
constexpr int TOT   = 3 * VOL;        // 12,288,000
constexpr int ROWS  = NV + 2 * RAD;   // 184
constexpr int PITCH = 17;             // float2 per row (pad: 16+1)
constexpr int OPT   = 10;             // conv-axis outputs per thread
constexpr int WIN   = OPT + KS - 1;   // 34

__device__ __forceinline__ float2 pkfma(float2 acc, float2 g2, float2 v) {
    // acc = g2 * v + acc, elementwise packed fp32 (VOP3P)
    asm("v_pk_fma_f32 %0, %1, %2, %0" : "+v"(acc) : "v"(g2), "v"(v));
    return acc;
}

// g1[i] = sum_{j,k} g3[i,j,k]  (since sum(g1)=1).
__global__ void extract_g1(const float* __restrict__ k3, float* __restrict__ g1) {
    int i = blockIdx.x;      // 0..24
    int t = threadIdx.x;     // 0..63
    float s = 0.f;
    for (int e = t; e < KS * KS; e += 64) s += k3[i * KS * KS + e];
#pragma unroll
    for (int off = 32; off > 0; off >>= 1) s += __shfl_down(s, off);
    if (t == 0) g1[i] = s;
}

// ---------------- W pass: conv axis = w, packed pairs along h ----------------
// Tile: T[wi][hp] = {x[h0+2hp][wv], x[h0+2hp+1][wv]},  wv = wi-12.
__global__ __launch_bounds__(256) void conv_w(const float* __restrict__ in,
                                              float* __restrict__ out,
                                              const float* __restrict__ g1) {
    __shared__ float2 T[ROWS][PITCH];
    float2 g2[KS];
#pragma unroll
    for (int t = 0; t < KS; ++t) { float g = g1[t]; g2[t] = make_float2(g, g); }

    int tid = threadIdx.x;
    int b   = blockIdx.x;
    int ht  = b % 5;
    int cd  = b / 5;               // c*160 + d
    int h0  = ht * 32;
    const float* base = in + (size_t)cd * PLANE;

    // stage (transposed): lanes along w for coalescing
    int wl = tid & 31, hq = tid >> 5;        // wl 0..31, hq 0..7
#pragma unroll
    for (int hh = 0; hh < 2; ++hh) {
        int hp = hq + hh * 8;                // 0..15
        const float* r0 = base + (h0 + 2 * hp) * NV;
#pragma unroll
        for (int ib = 0; ib < ROWS; ib += 32) {
            int i = ib + wl;
            if (i < ROWS) {
                int wv = i - RAD;
                float a = 0.f, bb = 0.f;
                if (wv >= 0 && wv < NV) { a = r0[wv]; bb = r0[NV + wv]; }
                T[i][hp] = make_float2(a, bb);
            }
        }
    }
    __syncthreads();

    int p  = tid & 15;             // h-pair
    int ct = tid >> 4;             // 0..15
    int wb = ct * OPT;
    float2 acc[OPT];
#pragma unroll
    for (int j = 0; j < OPT; ++j) acc[j] = make_float2(0.f, 0.f);
#pragma unroll
    for (int it = 0; it < WIN; ++it) {
        float2 v = T[wb + it][p];
#pragma unroll
        for (int j = 0; j < OPT; ++j) {
            int t = it - j;
            if (t >= 0 && t < KS) acc[j] = pkfma(acc[j], g2[t], v);
        }
    }
    float* ob = out + (size_t)cd * PLANE + (h0 + 2 * p) * NV;
#pragma unroll
    for (int j = 0; j < OPT; ++j) {
        ob[wb + j]      = acc[j].x;
        ob[NV + wb + j] = acc[j].y;
    }
}

// ---------------- H pass: conv axis = h, packed pairs along w ----------------
__global__ __launch_bounds__(256) void conv_h(const float* __restrict__ in,
                                              float* __restrict__ out,
                                              const float* __restrict__ g1) {
    __shared__ float2 T[ROWS][PITCH];
    float2 g2[KS];
#pragma unroll
    for (int t = 0; t < KS; ++t) { float g = g1[t]; g2[t] = make_float2(g, g); }

    int tid = threadIdx.x;
    int b   = blockIdx.x;
    int wt  = b % 5;
    int cd  = b / 5;               // c*160 + d
    int w0  = wt * 32;
    const float* base = in + (size_t)cd * PLANE + w0;

    int p  = tid & 15;
    int ct = tid >> 4;             // 0..15
#pragma unroll
    for (int i = ct; i < ROWS; i += 16) {
        int h = i - RAD;
        float2 v = make_float2(0.f, 0.f);
        if (h >= 0 && h < NV) v = *(const float2*)(base + h * NV + 2 * p);
        T[i][p] = v;
    }
    __syncthreads();

    int hb = ct * OPT;
    float2 acc[OPT];
#pragma unroll
    for (int j = 0; j < OPT; ++j) acc[j] = make_float2(0.f, 0.f);
#pragma unroll
    for (int it = 0; it < WIN; ++it) {
        float2 v = T[hb + it][p];
#pragma unroll
        for (int j = 0; j < OPT; ++j) {
            int t = it - j;
            if (t >= 0 && t < KS) acc[j] = pkfma(acc[j], g2[t], v);
        }
    }
    float* ob = out + (size_t)cd * PLANE + w0 + 2 * p;
#pragma unroll
    for (int j = 0; j < OPT; ++j)
        *(float2*)(ob + (hb + j) * NV) = acc[j];
}

// ---------------- D pass: conv axis = d, packed pairs along w ----------------
__global__ __launch_bounds__(256) void conv_d(const float* __restrict__ in,
                                              float* __restrict__ out,
                                              const float* __restrict__ g1) {
    __shared__ float2 T[ROWS][PITCH];
    float2 g2[KS];
#pragma unroll
    for (int t = 0; t < KS; ++t) { float g = g1[t]; g2[t] = make_float2(g, g); }

    int tid = threadIdx.x;
    int b   = blockIdx.x;
    int wt  = b % 5;
    int ch  = b / 5;               // c*160 + h
    int c   = ch / NV, h = ch % NV;
    int w0  = wt * 32;
    const float* base = in + (size_t)c * VOL + h * NV + w0;

    int p  = tid & 15;
    int ct = tid >> 4;
#pragma unroll
    for (int i = ct; i < ROWS; i += 16) {
        int d = i - RAD;
        float2 v = make_float2(0.f, 0.f);
        if (d >= 0 && d < NV) v = *(const float2*)(base + (size_t)d * PLANE + 2 * p);
        T[i][p] = v;
    }
    __syncthreads();

    int db = ct * OPT;
    float2 acc[OPT];
#pragma unroll
    for (int j = 0; j < OPT; ++j) acc[j] = make_float2(0.f, 0.f);
#pragma unroll
    for (int it = 0; it < WIN; ++it) {
        float2 v = T[db + it][p];
#pragma unroll
        for (int j = 0; j < OPT; ++j) {
            int t = it - j;
            if (t >= 0 && t < KS) acc[j] = pkfma(acc[j], g2[t], v);
        }
    }
    float* ob = out + (size_t)c * VOL + h * NV + w0 + 2 * p;
#pragma unroll
    for (int j = 0; j < OPT; ++j)
        *(float2*)(ob + (size_t)(db + j) * PLANE) = acc[j];
}

// Fallback (only if ws too small): direct 25^3-tap depthwise conv.
__global__ __launch_bounds__(256) void conv3d_direct(const float* __restrict__ x,
                                                     const float* __restrict__ k3,
                                                     float* __restrict__ out) {
    int idx = blockIdx.x * 256 + threadIdx.x;
    if (idx >= TOT) return;
    int w = idx % NV;
    int t = idx / NV;
    int h = t % NV; t /= NV;
    int d = t % NV;
    int c = t / NV;
    const float* kc = k3 + c * (KS * KS * KS);
    float acc = 0.f;
    for (int i = 0; i < KS; ++i) {
        int dd = d + i - RAD;
        if (dd < 0 || dd >= NV) continue;
        for (int j = 0; j < KS; ++j) {
            int hh = h + j - RAD;
            if (hh < 0 || hh >= NV) continue;
            const float* xr = x + (c * NV + dd) * NV * NV + hh * NV + (w - RAD);
            const float* kr = kc + (i * KS + j) * KS;
            int k0 = (RAD - w) > 0 ? (RAD - w) : 0;
            int k1 = (NV + RAD - w) < KS ? (NV + RAD - w) : KS;
            for (int k = k0; k < k1; ++k) acc += kr[k] * xr[k];
        }
    }
    out[idx] = acc;
}

extern "C" void kernel_launch(void* const* d_in, const int* in_sizes, int n_in,
                              void* d_out, int out_size, void* d_ws, size_t ws_size,
                              hipStream_t stream) {
    const float* x  = (const float*)d_in[0];
    const float* k3 = (const float*)d_in[1];
    float* out = (float*)d_out;

    size_t need = 4096 + (size_t)TOT * sizeof(float);
    if (ws_size >= need) {
        float* g1  = (float*)d_ws;
        float* tmp = (float*)((char*)d_ws + 4096);
        extract_g1<<<KS, 64, 0, stream>>>(k3, g1);
        conv_w<<<480 * 5, 256, 0, stream>>>(x, out, g1);    // x   -> out
        conv_h<<<480 * 5, 256, 0, stream>>>(out, tmp, g1);  // out -> tmp
        conv_d<<<480 * 5, 256, 0, stream>>>(tmp, out, g1);  // tmp -> out
    } else {
        conv3d_direct<<<(TOT + 255) / 256, 256, 0, stream>>>(x, k3, out);
    }
}